// Round 1
// baseline (440.594 us; speedup 1.0000x reference)
//
#include <hip/hip_runtime.h>
#include <hip/hip_bf16.h>
#include <stdint.h>

using bf16 = __hip_bfloat16;
using bf16x8 = __attribute__((ext_vector_type(8))) short;
using f32x4  = __attribute__((ext_vector_type(4))) float;
using short4v = __attribute__((ext_vector_type(4))) short;

#define EPSF 1e-6f

__device__ __forceinline__ unsigned short f2bu(float x) {
  union { bf16 h; unsigned short u; } cvt;
  cvt.h = __float2bfloat16(x);
  return cvt.u;
}

typedef __attribute__((address_space(3))) void as3_void;
typedef const __attribute__((address_space(1))) void as1_void;

__device__ __forceinline__ void gload_lds16(const void* g, void* l) {
  as1_void* gp = (as1_void*)(uintptr_t)g;
  as3_void* lp = (as3_void*)(uint32_t)(uintptr_t)l;  // generic LDS ptr low 32 bits = LDS offset
  __builtin_amdgcn_global_load_lds(gp, lp, 16, 0, 0);
}

// ---------------- rope tables: cos/sin [1024][32] ----------------
__global__ void rope_tab(float* __restrict__ cosT, float* __restrict__ sinT) {
  const int i = blockIdx.x * 256 + threadIdx.x;   // 32768 = 1024*32
  const int n = i >> 5, fi = i & 31;
  const float invf = powf(10000.f, -(float)fi * (1.f / 32.f));
  const float ang = (float)n * invf;
  cosT[i] = cosf(ang);
  sinT[i] = sinf(ang);
}

// ---------------- mods = silu(c) @ ada_w + ada_b : [4][6144] ----------------
__global__ void __launch_bounds__(256) ada_mods(const float* __restrict__ cc,
                                                const float* __restrict__ adaw,
                                                const float* __restrict__ adab,
                                                float* __restrict__ mods) {
  __shared__ float sc[4096];
  __shared__ float red[256 * 4];
  const int t = threadIdx.x;
  for (int i = t; i < 4096; i += 256) {
    const float v = cc[i];
    sc[i] = v / (1.f + __expf(-v));
  }
  __syncthreads();
  const int colL = t & 31, kg = t >> 5;
  const int col = blockIdx.x * 32 + colL;
  float a0 = 0.f, a1 = 0.f, a2 = 0.f, a3 = 0.f;
  const int k0 = kg * 128;
  for (int k = k0; k < k0 + 128; ++k) {
    const float awv = adaw[(size_t)k * 6144 + col];
    a0 += sc[k] * awv; a1 += sc[1024 + k] * awv;
    a2 += sc[2048 + k] * awv; a3 += sc[3072 + k] * awv;
  }
  red[t * 4 + 0] = a0; red[t * 4 + 1] = a1; red[t * 4 + 2] = a2; red[t * 4 + 3] = a3;
  __syncthreads();
  if (kg == 0) {
    float s0 = 0, s1 = 0, s2 = 0, s3 = 0;
#pragma unroll
    for (int gg = 0; gg < 8; ++gg) {
      const int idx = (gg * 32 + t) * 4;
      s0 += red[idx]; s1 += red[idx + 1]; s2 += red[idx + 2]; s3 += red[idx + 3];
    }
    const float bb = adab[col];
    mods[0 * 6144 + col] = s0 + bb;
    mods[1 * 6144 + col] = s1 + bb;
    mods[2 * 6144 + col] = s2 + bb;
    mods[3 * 6144 + col] = s3 + bb;
  }
}

// ---------------- y = rmsnorm(x,w)*(1+sc)+sh  -> bf16 ----------------
__global__ void __launch_bounds__(256) norm_mod(const float* __restrict__ X,
                                                const float* __restrict__ wgt,
                                                const float* __restrict__ mods,
                                                int sh_off, int sc_off,
                                                bf16* __restrict__ Y) {
  __shared__ float red[4];
  const int row = blockIdx.x, t = threadIdx.x, l = t & 63, wv = t >> 6;
  const float4 xv = ((const float4*)(X + (size_t)row * 1024))[t];
  float ss = xv.x * xv.x + xv.y * xv.y + xv.z * xv.z + xv.w * xv.w;
#pragma unroll
  for (int off = 1; off < 64; off <<= 1) ss += __shfl_xor(ss, off);
  if (l == 0) red[wv] = ss;
  __syncthreads();
  ss = (red[0] + red[1]) + (red[2] + red[3]);
  const float rs = rsqrtf(ss * (1.f / 1024.f) + EPSF);
  const int b = row >> 10;
  const float* mb = mods + b * 6144;
  const int c0 = t * 4;
  float vals[4] = {xv.x, xv.y, xv.z, xv.w};
  short4v yv;
#pragma unroll
  for (int j = 0; j < 4; j++) {
    const int cc = c0 + j;
    const float y = vals[j] * rs * wgt[cc] * (1.f + mb[sc_off + cc]) + mb[sh_off + cc];
    yv[j] = (short)f2bu(y);
  }
  *(short4v*)(Y + (size_t)row * 1024 + c0) = yv;
}

// ---------------- transpose + cast f32[R][Cc] -> bf16 dst[Cc][ldd] (zero pad r>=R) --------
__global__ void __launch_bounds__(256) transpose_cast(const float* __restrict__ src, int R, int Cc,
                                                      bf16* __restrict__ dst, int ldd) {
  __shared__ float tile[32][33];
  const int tx = threadIdx.x & 31, ty = threadIdx.x >> 5;
  const int ct = blockIdx.x * 32, rt = blockIdx.y * 32;
#pragma unroll
  for (int kk = 0; kk < 4; ++kk) {
    const int r = rt + ty + kk * 8;
    float v = 0.f;
    if (r < R && (ct + tx) < Cc) v = src[(size_t)r * Cc + ct + tx];
    tile[ty + kk * 8][tx] = v;
  }
  __syncthreads();
#pragma unroll
  for (int kk = 0; kk < 4; ++kk) {
    const int c = ct + ty + kk * 8;
    const int r = rt + tx;
    if (c < Cc && r < ldd) dst[(size_t)c * ldd + r] = __float2bfloat16(tile[tx][ty + kk * 8]);
  }
}

// ---------------- GEMM C = A[M,K](bf16) @ Bt[N,K]^T(bf16), 128x128 tile ----------------
// EPI 0: bf16 store (col<Nreal).  EPI 1: f32 out = resid + gate*(acc+bias).
// EPI 3: bf16 out = silu(h1)*acc (zero for col>=Nreal).  EPI 4: f32 out = resid + gate*acc.
template <int EPI>
__global__ void __launch_bounds__(256) gemm_bt(const bf16* __restrict__ A, int lda,
                                               const bf16* __restrict__ Bt, int ldb,
                                               int K, int Nreal, int ldc,
                                               bf16* __restrict__ outb,
                                               float* __restrict__ outf,
                                               const float* __restrict__ resid,
                                               const float* __restrict__ gate,
                                               const float* __restrict__ bias,
                                               const bf16* __restrict__ h1, int ldh) {
  __shared__ bf16 As[128 * 32];
  __shared__ bf16 Bs[128 * 32];
  const int t = threadIdx.x, l = t & 63, w = t >> 6;
  const int g = l >> 4, cl = l & 15;
  const int m0 = blockIdx.y * 128, n0 = blockIdx.x * 128;
  const int wm = w >> 1, wn = w & 1;
  f32x4 acc[4][4] = {};
  const bf16* ap = A + (size_t)(m0 + (t >> 2)) * lda + (t & 3) * 8;
  const bf16* bp = Bt + (size_t)(n0 + (t >> 2)) * ldb + (t & 3) * 8;
  char* asb = (char*)As + w * 1024;
  char* bsb = (char*)Bs + w * 1024;
  const int nk = K >> 5;
  for (int kt = 0; kt < nk; ++kt) {
    __syncthreads();
    gload_lds16(ap, asb);
    gload_lds16(ap + (size_t)64 * lda, asb + 4096);
    gload_lds16(bp, bsb);
    gload_lds16(bp + (size_t)64 * ldb, bsb + 4096);
    ap += 32; bp += 32;
    __syncthreads();
    bf16x8 af[4], bfr[4];
#pragma unroll
    for (int i = 0; i < 4; i++)
      af[i] = *(const bf16x8*)&As[(wm * 64 + i * 16 + cl) * 32 + g * 8];
#pragma unroll
    for (int i = 0; i < 4; i++)
      bfr[i] = *(const bf16x8*)&Bs[(wn * 64 + i * 16 + cl) * 32 + g * 8];
#pragma unroll
    for (int mi = 0; mi < 4; mi++)
#pragma unroll
      for (int ni = 0; ni < 4; ni++)
        acc[mi][ni] = __builtin_amdgcn_mfma_f32_16x16x32_bf16(af[mi], bfr[ni], acc[mi][ni], 0, 0, 0);
  }
#pragma unroll
  for (int mi = 0; mi < 4; mi++) {
#pragma unroll
    for (int ni = 0; ni < 4; ni++) {
      const int c = n0 + wn * 64 + ni * 16 + cl;
#pragma unroll
      for (int j = 0; j < 4; j++) {
        const int r = m0 + wm * 64 + mi * 16 + g * 4 + j;
        const float v = acc[mi][ni][j];
        if constexpr (EPI == 0) {
          if (c < Nreal) outb[(size_t)r * ldc + c] = __float2bfloat16(v);
        } else if constexpr (EPI == 1) {
          const int b = r >> 10;
          outf[(size_t)r * ldc + c] = resid[(size_t)r * ldc + c] + gate[b * 6144 + c] * (v + bias[c]);
        } else if constexpr (EPI == 3) {
          if (c < Nreal) {
            const float hv = __bfloat162float(h1[(size_t)r * ldh + c]);
            const float sl = hv / (1.f + __expf(-hv));
            outb[(size_t)r * ldc + c] = __float2bfloat16(sl * v);
          } else {
            outb[(size_t)r * ldc + c] = __float2bfloat16(0.f);
          }
        } else if constexpr (EPI == 4) {
          const int b = r >> 10;
          outf[(size_t)r * ldc + c] = resid[(size_t)r * ldc + c] + gate[b * 6144 + c] * v;
        }
      }
    }
  }
}

// ---------------- qkv post: per-head q/k rmsnorm + rope, scatter to [BH][N][D] ----------
__global__ void __launch_bounds__(256) qkv_post(const bf16* __restrict__ qkv,
                                                const float* __restrict__ cosT,
                                                const float* __restrict__ sinT,
                                                const float* __restrict__ qnw,
                                                const float* __restrict__ knw,
                                                bf16* __restrict__ Qo, bf16* __restrict__ Ko,
                                                bf16* __restrict__ Vo) {
  const int t = threadIdx.x, l = t & 63, wv = t >> 6;
  const int row = blockIdx.x * 4 + wv;   // = token*16 + h
  const int token = row >> 4, h = row & 15;
  const int b = token >> 10, n = token & 1023;
  const int d = l;
  const bf16* base = qkv + (size_t)token * 3072 + h * 64 + d;
  float q = __bfloat162float(base[0]);
  float k = __bfloat162float(base[1024]);
  const bf16 v = base[2048];
  float sq = q * q, sk = k * k;
#pragma unroll
  for (int off = 1; off < 64; off <<= 1) {
    sq += __shfl_xor(sq, off);
    sk += __shfl_xor(sk, off);
  }
  q *= rsqrtf(sq * (1.f / 64.f) + EPSF) * qnw[d];
  k *= rsqrtf(sk * (1.f / 64.f) + EPSF) * knw[d];
  const float cs = cosT[n * 32 + (d & 31)];
  const float sn = sinT[n * 32 + (d & 31)];
  const float qx = __shfl_xor(q, 32), kx = __shfl_xor(k, 32);
  const float sgn = (d < 32) ? -1.f : 1.f;
  const float qo = q * cs + sgn * qx * sn;
  const float ko = k * cs + sgn * kx * sn;
  const size_t ob = ((size_t)(b * 16 + h) * 1024 + n) * 64 + d;
  Qo[ob] = __float2bfloat16(qo);
  Ko[ob] = __float2bfloat16(ko);
  Vo[ob] = v;
}

// ---------------- flash attention: grid (16 qtiles, 64 bh), 4 waves * 16 q-rows -------
__global__ void __launch_bounds__(256) attn_fwd(const bf16* __restrict__ Qb,
                                                const bf16* __restrict__ Kb,
                                                const bf16* __restrict__ Vb,
                                                bf16* __restrict__ Ob) {
  __shared__ unsigned short Ks[32 * 72];   // [kv][d] rows padded to 72 (stride 8*odd -> conflict-free)
  __shared__ unsigned short Vt[64 * 56];   // [d][kv] transposed, stride 56
  __shared__ unsigned short Ps[4 * 16 * 72]; // per-wave P tile [16 q][32 kv], stride 72
  const int t = threadIdx.x, l = t & 63, w = t >> 6;
  const int g = l >> 4, cl = l & 15;
  const int bh = blockIdx.y;
  const int q0 = blockIdx.x * 64;
  const bf16* Qg = Qb + (size_t)bh * 65536;
  const bf16* Kg = Kb + (size_t)bh * 65536;
  const bf16* Vg = Vb + (size_t)bh * 65536;
  const int qrow = q0 + w * 16 + cl;
  const bf16x8 aq0 = *(const bf16x8*)(Qg + (size_t)qrow * 64 + g * 8);
  const bf16x8 aq1 = *(const bf16x8*)(Qg + (size_t)qrow * 64 + 32 + g * 8);
  float mrow[4] = {-1e30f, -1e30f, -1e30f, -1e30f};
  float lrow[4] = {0.f, 0.f, 0.f, 0.f};
  f32x4 o0 = {0, 0, 0, 0}, o1 = {0, 0, 0, 0}, o2 = {0, 0, 0, 0}, o3 = {0, 0, 0, 0};
  for (int kvt = 0; kvt < 32; ++kvt) {
    const int kv0 = kvt * 32;
    __syncthreads();
    {
      const int kv = t >> 3, d0 = (t & 7) * 8;
      const bf16x8 kvv = *(const bf16x8*)(Kg + (size_t)(kv0 + kv) * 64 + d0);
      const bf16x8 vvv = *(const bf16x8*)(Vg + (size_t)(kv0 + kv) * 64 + d0);
      *(bf16x8*)&Ks[kv * 72 + d0] = kvv;
#pragma unroll
      for (int j = 0; j < 8; j++) Vt[(d0 + j) * 56 + kv] = (unsigned short)vvv[j];
    }
    __syncthreads();
    f32x4 s0 = {0, 0, 0, 0}, s1 = {0, 0, 0, 0};
    bf16x8 bk;
    bk = *(const bf16x8*)&Ks[cl * 72 + g * 8];
    s0 = __builtin_amdgcn_mfma_f32_16x16x32_bf16(aq0, bk, s0, 0, 0, 0);
    bk = *(const bf16x8*)&Ks[cl * 72 + 32 + g * 8];
    s0 = __builtin_amdgcn_mfma_f32_16x16x32_bf16(aq1, bk, s0, 0, 0, 0);
    bk = *(const bf16x8*)&Ks[(16 + cl) * 72 + g * 8];
    s1 = __builtin_amdgcn_mfma_f32_16x16x32_bf16(aq0, bk, s1, 0, 0, 0);
    bk = *(const bf16x8*)&Ks[(16 + cl) * 72 + 32 + g * 8];
    s1 = __builtin_amdgcn_mfma_f32_16x16x32_bf16(aq1, bk, s1, 0, 0, 0);
#pragma unroll
    for (int j = 0; j < 4; j++) {
      const float v0 = s0[j] * 0.125f, v1 = s1[j] * 0.125f;
      float pm = fmaxf(v0, v1);
#pragma unroll
      for (int off = 1; off < 16; off <<= 1) pm = fmaxf(pm, __shfl_xor(pm, off));
      const float nm = fmaxf(mrow[j], pm);
      const float al = __expf(mrow[j] - nm);
      const float p0 = __expf(v0 - nm), p1 = __expf(v1 - nm);
      float rs = p0 + p1;
#pragma unroll
      for (int off = 1; off < 16; off <<= 1) rs += __shfl_xor(rs, off);
      lrow[j] = lrow[j] * al + rs;
      mrow[j] = nm;
      o0[j] *= al; o1[j] *= al; o2[j] *= al; o3[j] *= al;
      Ps[w * 1152 + (g * 4 + j) * 72 + cl] = f2bu(p0);
      Ps[w * 1152 + (g * 4 + j) * 72 + 16 + cl] = f2bu(p1);
    }
    const bf16x8 apf = *(const bf16x8*)&Ps[w * 1152 + cl * 72 + g * 8];
    bf16x8 bv;
    bv = *(const bf16x8*)&Vt[cl * 56 + g * 8];
    o0 = __builtin_amdgcn_mfma_f32_16x16x32_bf16(apf, bv, o0, 0, 0, 0);
    bv = *(const bf16x8*)&Vt[(16 + cl) * 56 + g * 8];
    o1 = __builtin_amdgcn_mfma_f32_16x16x32_bf16(apf, bv, o1, 0, 0, 0);
    bv = *(const bf16x8*)&Vt[(32 + cl) * 56 + g * 8];
    o2 = __builtin_amdgcn_mfma_f32_16x16x32_bf16(apf, bv, o2, 0, 0, 0);
    bv = *(const bf16x8*)&Vt[(48 + cl) * 56 + g * 8];
    o3 = __builtin_amdgcn_mfma_f32_16x16x32_bf16(apf, bv, o3, 0, 0, 0);
  }
  const int b = bh >> 4, h = bh & 15;
#pragma unroll
  for (int j = 0; j < 4; j++) {
    const float inv = 1.f / lrow[j];
    const int q = q0 + w * 16 + g * 4 + j;
    const size_t base = ((size_t)(b * 1024 + q) * 16 + h) * 64;
    Ob[base + cl] = __float2bfloat16(o0[j] * inv);
    Ob[base + 16 + cl] = __float2bfloat16(o1[j] * inv);
    Ob[base + 32 + cl] = __float2bfloat16(o2[j] * inv);
    Ob[base + 48 + cl] = __float2bfloat16(o3[j] * inv);
  }
}

// ---------------- launch ----------------
extern "C" void kernel_launch(void* const* d_in, const int* in_sizes, int n_in,
                              void* d_out, int out_size, void* d_ws, size_t ws_size,
                              hipStream_t stream) {
  const float* x     = (const float*)d_in[0];
  const float* c     = (const float*)d_in[1];
  const float* n1w   = (const float*)d_in[2];
  const float* n2w   = (const float*)d_in[3];
  const float* qkvw  = (const float*)d_in[4];
  const float* projw = (const float*)d_in[5];
  const float* projb = (const float*)d_in[6];
  const float* qnw   = (const float*)d_in[7];
  const float* knw   = (const float*)d_in[8];
  const float* w1    = (const float*)d_in[9];
  const float* w2    = (const float*)d_in[10];
  const float* w3    = (const float*)d_in[11];
  const float* adaw  = (const float*)d_in[12];
  const float* adab  = (const float*)d_in[13];
  float* outp = (float*)d_out;
  char* ws = (char*)d_ws;
  if (ws_size < 93159424u) return;

  float* ropeC = (float*)(ws + 0);          // 131072
  float* ropeS = (float*)(ws + 131072);     // 131072
  float* mods  = (float*)(ws + 262144);     // 98304
  bf16* xmod   = (bf16*)(ws + 360448);      // 8388608
  bf16* qkvwt  = (bf16*)(ws + 8749056);     // 6291456  [3072][1024]
  bf16* projwt = (bf16*)(ws + 15040512);    // 2097152  [1024][1024]
  bf16* w1t    = (bf16*)(ws + 17137664);    // 5767168  [2816][1024] (rows>=2730 garbage, unused)
  bf16* w3t    = (bf16*)(ws + 22904832);    // 5767168
  bf16* w2t    = (bf16*)(ws + 28672000);    // 5767168  [1024][2816] (cols>=2730 zero)
  bf16* qkv    = (bf16*)(ws + 34439168);    // 25165824 [4096][3072]
  bf16* h1     = (bf16*)(ws + 34439168);    // reuse: [4096][2730]
  bf16* qb     = (bf16*)(ws + 59604992);    // 8388608 [64][1024][64]
  bf16* gbuf   = (bf16*)(ws + 59604992);    // reuse q/k/v: [4096][2816]
  bf16* kb     = (bf16*)(ws + 67993600);    // 8388608
  bf16* vb     = (bf16*)(ws + 76382208);    // 8388608
  bf16* ob     = (bf16*)(ws + 84770816);    // 8388608 [4096][1024] ([B][N][H][D])

  rope_tab<<<128, 256, 0, stream>>>(ropeC, ropeS);
  ada_mods<<<192, 256, 0, stream>>>(c, adaw, adab, mods);
  transpose_cast<<<dim3(96, 32), 256, 0, stream>>>(qkvw, 1024, 3072, qkvwt, 1024);
  transpose_cast<<<dim3(32, 32), 256, 0, stream>>>(projw, 1024, 1024, projwt, 1024);
  transpose_cast<<<dim3(86, 32), 256, 0, stream>>>(w1, 1024, 2730, w1t, 1024);
  transpose_cast<<<dim3(86, 32), 256, 0, stream>>>(w3, 1024, 2730, w3t, 1024);
  transpose_cast<<<dim3(32, 88), 256, 0, stream>>>(w2, 2730, 1024, w2t, 2816);

  // attention branch
  norm_mod<<<4096, 256, 0, stream>>>(x, n1w, mods, 0, 1024, xmod);
  gemm_bt<0><<<dim3(24, 32), 256, 0, stream>>>(xmod, 1024, qkvwt, 1024, 1024, 3072, 3072,
                                               qkv, nullptr, nullptr, nullptr, nullptr, nullptr, 0);
  qkv_post<<<16384, 256, 0, stream>>>(qkv, ropeC, ropeS, qnw, knw, qb, kb, vb);
  attn_fwd<<<dim3(16, 64), 256, 0, stream>>>(qb, kb, vb, ob);
  gemm_bt<1><<<dim3(8, 32), 256, 0, stream>>>(ob, 1024, projwt, 1024, 1024, 1024, 1024,
                                              nullptr, outp, x, mods + 2048, projb, nullptr, 0);

  // MLP branch
  norm_mod<<<4096, 256, 0, stream>>>(outp, n2w, mods, 3072, 4096, xmod);
  gemm_bt<0><<<dim3(22, 32), 256, 0, stream>>>(xmod, 1024, w1t, 1024, 1024, 2730, 2730,
                                               h1, nullptr, nullptr, nullptr, nullptr, nullptr, 0);
  gemm_bt<3><<<dim3(22, 32), 256, 0, stream>>>(xmod, 1024, w3t, 1024, 1024, 2730, 2816,
                                               gbuf, nullptr, nullptr, nullptr, nullptr, h1, 2730);
  gemm_bt<4><<<dim3(8, 32), 256, 0, stream>>>(gbuf, 2816, w2t, 2816, 2816, 1024, 1024,
                                              nullptr, outp, outp, mods + 5120, nullptr, nullptr, 0);
}

// Round 2
// 405.398 us; speedup vs baseline: 1.0868x; 1.0868x over previous
//
#include <hip/hip_runtime.h>
#include <hip/hip_bf16.h>
#include <stdint.h>

using bf16 = __hip_bfloat16;
using bf16x8 = __attribute__((ext_vector_type(8))) short;
using f32x4  = __attribute__((ext_vector_type(4))) float;
using short4v = __attribute__((ext_vector_type(4))) short;

#define EPSF 1e-6f

__device__ __forceinline__ unsigned short f2bu(float x) {
  union { bf16 h; unsigned short u; } cvt;
  cvt.h = __float2bfloat16(x);
  return cvt.u;
}

typedef __attribute__((address_space(3))) void as3_void;
typedef const __attribute__((address_space(1))) void as1_void;

__device__ __forceinline__ void gload_lds16(const void* g, void* l) {
  as1_void* gp = (as1_void*)(uintptr_t)g;
  as3_void* lp = (as3_void*)(uint32_t)(uintptr_t)l;  // generic LDS ptr low 32 bits = LDS offset
  __builtin_amdgcn_global_load_lds(gp, lp, 16, 0, 0);
}

// ---------------- rope tables: cos/sin [1024][32] ----------------
__global__ void rope_tab(float* __restrict__ cosT, float* __restrict__ sinT) {
  const int i = blockIdx.x * 256 + threadIdx.x;   // 32768 = 1024*32
  const int n = i >> 5, fi = i & 31;
  const float invf = powf(10000.f, -(float)fi * (1.f / 32.f));
  const float ang = (float)n * invf;
  cosT[i] = cosf(ang);
  sinT[i] = sinf(ang);
}

// ---------------- mods = silu(c) @ ada_w + ada_b : [4][6144] ----------------
__global__ void __launch_bounds__(256) ada_mods(const float* __restrict__ cc,
                                                const float* __restrict__ adaw,
                                                const float* __restrict__ adab,
                                                float* __restrict__ mods) {
  __shared__ float sc[4096];
  __shared__ float red[256 * 4];
  const int t = threadIdx.x;
  for (int i = t; i < 4096; i += 256) {
    const float v = cc[i];
    sc[i] = v / (1.f + __expf(-v));
  }
  __syncthreads();
  const int colL = t & 31, kg = t >> 5;
  const int col = blockIdx.x * 32 + colL;
  float a0 = 0.f, a1 = 0.f, a2 = 0.f, a3 = 0.f;
  const int k0 = kg * 128;
  for (int k = k0; k < k0 + 128; ++k) {
    const float awv = adaw[(size_t)k * 6144 + col];
    a0 += sc[k] * awv; a1 += sc[1024 + k] * awv;
    a2 += sc[2048 + k] * awv; a3 += sc[3072 + k] * awv;
  }
  red[t * 4 + 0] = a0; red[t * 4 + 1] = a1; red[t * 4 + 2] = a2; red[t * 4 + 3] = a3;
  __syncthreads();
  if (kg == 0) {
    float s0 = 0, s1 = 0, s2 = 0, s3 = 0;
#pragma unroll
    for (int gg = 0; gg < 8; ++gg) {
      const int idx = (gg * 32 + t) * 4;
      s0 += red[idx]; s1 += red[idx + 1]; s2 += red[idx + 2]; s3 += red[idx + 3];
    }
    const float bb = adab[col];
    mods[0 * 6144 + col] = s0 + bb;
    mods[1 * 6144 + col] = s1 + bb;
    mods[2 * 6144 + col] = s2 + bb;
    mods[3 * 6144 + col] = s3 + bb;
  }
}

// ---------------- y = rmsnorm(x,w)*(1+sc)+sh  -> bf16 ----------------
__global__ void __launch_bounds__(256) norm_mod(const float* __restrict__ X,
                                                const float* __restrict__ wgt,
                                                const float* __restrict__ mods,
                                                int sh_off, int sc_off,
                                                bf16* __restrict__ Y) {
  __shared__ float red[4];
  const int row = blockIdx.x, t = threadIdx.x, l = t & 63, wv = t >> 6;
  const float4 xv = ((const float4*)(X + (size_t)row * 1024))[t];
  float ss = xv.x * xv.x + xv.y * xv.y + xv.z * xv.z + xv.w * xv.w;
#pragma unroll
  for (int off = 1; off < 64; off <<= 1) ss += __shfl_xor(ss, off);
  if (l == 0) red[wv] = ss;
  __syncthreads();
  ss = (red[0] + red[1]) + (red[2] + red[3]);
  const float rs = rsqrtf(ss * (1.f / 1024.f) + EPSF);
  const int b = row >> 10;
  const float* mb = mods + b * 6144;
  const int c0 = t * 4;
  float vals[4] = {xv.x, xv.y, xv.z, xv.w};
  short4v yv;
#pragma unroll
  for (int j = 0; j < 4; j++) {
    const int cc = c0 + j;
    const float y = vals[j] * rs * wgt[cc] * (1.f + mb[sc_off + cc]) + mb[sh_off + cc];
    yv[j] = (short)f2bu(y);
  }
  *(short4v*)(Y + (size_t)row * 1024 + c0) = yv;
}

// ---------------- transpose + cast f32[R][Cc] -> bf16 dst[Cc][ldd] (zero pad r>=R) --------
__global__ void __launch_bounds__(256) transpose_cast(const float* __restrict__ src, int R, int Cc,
                                                      bf16* __restrict__ dst, int ldd) {
  __shared__ float tile[32][33];
  const int tx = threadIdx.x & 31, ty = threadIdx.x >> 5;
  const int ct = blockIdx.x * 32, rt = blockIdx.y * 32;
#pragma unroll
  for (int kk = 0; kk < 4; ++kk) {
    const int r = rt + ty + kk * 8;
    float v = 0.f;
    if (r < R && (ct + tx) < Cc) v = src[(size_t)r * Cc + ct + tx];
    tile[ty + kk * 8][tx] = v;
  }
  __syncthreads();
#pragma unroll
  for (int kk = 0; kk < 4; ++kk) {
    const int c = ct + ty + kk * 8;
    const int r = rt + tx;
    if (c < Cc && r < ldd) dst[(size_t)c * ldd + r] = __float2bfloat16(tile[tx][ty + kk * 8]);
  }
}

// ---------------- GEMM C = A[M,K](bf16) @ Bt[N,K]^T(bf16), 128x128 tile ----------------
// EPI 0: bf16 store (col<Nreal).  EPI 1: f32 out = resid + gate*(acc+bias).
// EPI 3: bf16 out = silu(h1)*acc (zero for col>=Nreal).  EPI 4: f32 out = resid + gate*acc.
template <int EPI>
__global__ void __launch_bounds__(256) gemm_bt(const bf16* __restrict__ A, int lda,
                                               const bf16* __restrict__ Bt, int ldb,
                                               int K, int Nreal, int ldc,
                                               bf16* __restrict__ outb,
                                               float* __restrict__ outf,
                                               const float* __restrict__ resid,
                                               const float* __restrict__ gate,
                                               const float* __restrict__ bias,
                                               const bf16* __restrict__ h1, int ldh) {
  __shared__ bf16 As[128 * 32];
  __shared__ bf16 Bs[128 * 32];
  const int t = threadIdx.x, l = t & 63, w = t >> 6;
  const int g = l >> 4, cl = l & 15;
  const int m0 = blockIdx.y * 128, n0 = blockIdx.x * 128;
  const int wm = w >> 1, wn = w & 1;
  f32x4 acc[4][4] = {};
  const bf16* ap = A + (size_t)(m0 + (t >> 2)) * lda + (t & 3) * 8;
  const bf16* bp = Bt + (size_t)(n0 + (t >> 2)) * ldb + (t & 3) * 8;
  char* asb = (char*)As + w * 1024;
  char* bsb = (char*)Bs + w * 1024;
  const int nk = K >> 5;
  for (int kt = 0; kt < nk; ++kt) {
    __syncthreads();
    gload_lds16(ap, asb);
    gload_lds16(ap + (size_t)64 * lda, asb + 4096);
    gload_lds16(bp, bsb);
    gload_lds16(bp + (size_t)64 * ldb, bsb + 4096);
    ap += 32; bp += 32;
    __syncthreads();
    bf16x8 af[4], bfr[4];
#pragma unroll
    for (int i = 0; i < 4; i++)
      af[i] = *(const bf16x8*)&As[(wm * 64 + i * 16 + cl) * 32 + g * 8];
#pragma unroll
    for (int i = 0; i < 4; i++)
      bfr[i] = *(const bf16x8*)&Bs[(wn * 64 + i * 16 + cl) * 32 + g * 8];
#pragma unroll
    for (int mi = 0; mi < 4; mi++)
#pragma unroll
      for (int ni = 0; ni < 4; ni++)
        acc[mi][ni] = __builtin_amdgcn_mfma_f32_16x16x32_bf16(af[mi], bfr[ni], acc[mi][ni], 0, 0, 0);
  }
#pragma unroll
  for (int mi = 0; mi < 4; mi++) {
#pragma unroll
    for (int ni = 0; ni < 4; ni++) {
      const int c = n0 + wn * 64 + ni * 16 + cl;
#pragma unroll
      for (int j = 0; j < 4; j++) {
        const int r = m0 + wm * 64 + mi * 16 + g * 4 + j;
        const float v = acc[mi][ni][j];
        if constexpr (EPI == 0) {
          if (c < Nreal) outb[(size_t)r * ldc + c] = __float2bfloat16(v);
        } else if constexpr (EPI == 1) {
          const int b = r >> 10;
          outf[(size_t)r * ldc + c] = resid[(size_t)r * ldc + c] + gate[b * 6144 + c] * (v + bias[c]);
        } else if constexpr (EPI == 3) {
          if (c < Nreal) {
            const float hv = __bfloat162float(h1[(size_t)r * ldh + c]);
            const float sl = hv / (1.f + __expf(-hv));
            outb[(size_t)r * ldc + c] = __float2bfloat16(sl * v);
          } else {
            outb[(size_t)r * ldc + c] = __float2bfloat16(0.f);
          }
        } else if constexpr (EPI == 4) {
          const int b = r >> 10;
          outf[(size_t)r * ldc + c] = resid[(size_t)r * ldc + c] + gate[b * 6144 + c] * v;
        }
      }
    }
  }
}

// ---------------- qkv post: per-head q/k rmsnorm + rope, scatter to [BH][N][D] ----------
__global__ void __launch_bounds__(256) qkv_post(const bf16* __restrict__ qkv,
                                                const float* __restrict__ cosT,
                                                const float* __restrict__ sinT,
                                                const float* __restrict__ qnw,
                                                const float* __restrict__ knw,
                                                bf16* __restrict__ Qo, bf16* __restrict__ Ko,
                                                bf16* __restrict__ Vo) {
  const int t = threadIdx.x, l = t & 63, wv = t >> 6;
  const int row = blockIdx.x * 4 + wv;   // = token*16 + h
  const int token = row >> 4, h = row & 15;
  const int b = token >> 10, n = token & 1023;
  const int d = l;
  const bf16* base = qkv + (size_t)token * 3072 + h * 64 + d;
  float q = __bfloat162float(base[0]);
  float k = __bfloat162float(base[1024]);
  const bf16 v = base[2048];
  float sq = q * q, sk = k * k;
#pragma unroll
  for (int off = 1; off < 64; off <<= 1) {
    sq += __shfl_xor(sq, off);
    sk += __shfl_xor(sk, off);
  }
  q *= rsqrtf(sq * (1.f / 64.f) + EPSF) * qnw[d];
  k *= rsqrtf(sk * (1.f / 64.f) + EPSF) * knw[d];
  const float cs = cosT[n * 32 + (d & 31)];
  const float sn = sinT[n * 32 + (d & 31)];
  const float qx = __shfl_xor(q, 32), kx = __shfl_xor(k, 32);
  const float sgn = (d < 32) ? -1.f : 1.f;
  const float qo = q * cs + sgn * qx * sn;
  const float ko = k * cs + sgn * kx * sn;
  const size_t ob = ((size_t)(b * 16 + h) * 1024 + n) * 64 + d;
  Qo[ob] = __float2bfloat16(qo);
  Ko[ob] = __float2bfloat16(ko);
  Vo[ob] = v;
}

// ---------------- flash attention v2: grid (16 qtiles, 64 bh), 4 waves * 16 q-rows ------
// KVB=64. K staged via global_load_lds into linear [64][64] tile with XOR-swizzled
// d-slots (slot_phys = slot_log ^ (kv&7)) — swizzle applied on the GLOBAL source
// address (per-lane) AND on the LDS read address; LDS dest stays linear (rule #21).
// V staged via regs + transposed scalar writes, stride 66 (conflict-free writes).
__global__ void __launch_bounds__(256) attn_fwd(const bf16* __restrict__ Qb,
                                                const bf16* __restrict__ Kb,
                                                const bf16* __restrict__ Vb,
                                                bf16* __restrict__ Ob) {
  __shared__ char KsB[8192];                 // [64 kv][8 slots of 16B], slots xor-swizzled
  __shared__ unsigned short Vt[64 * 66];     // [d][kv] transposed, stride 66
  __shared__ unsigned short Ps[4 * 16 * 72]; // per-wave P tile [16 q][64 kv], stride 72
  const int t = threadIdx.x, l = t & 63, w = t >> 6;
  const int g = l >> 4, cl = l & 15;
  const int bh = blockIdx.y;
  const int q0 = blockIdx.x * 64;
  const bf16* Qg = Qb + (size_t)bh * 65536;
  const bf16* Kg = Kb + (size_t)bh * 65536;
  const bf16* Vg = Vb + (size_t)bh * 65536;
  const int qrow = q0 + w * 16 + cl;
  const bf16x8 aq0 = *(const bf16x8*)(Qg + (size_t)qrow * 64 + g * 8);
  const bf16x8 aq1 = *(const bf16x8*)(Qg + (size_t)qrow * 64 + 32 + g * 8);
  float mrow[4] = {-1e30f, -1e30f, -1e30f, -1e30f};
  float lrow[4] = {0.f, 0.f, 0.f, 0.f};
  f32x4 o[4] = {};
  // K staging geometry: wave w, lane l covers kv row (w*8 + (l>>3)) (+32 for round 2),
  // physical slot c = l&7; global d-slot loaded = c ^ (kv&7).
  const int kr_l = w * 8 + (l >> 3);
  const int ku = (l & 7) ^ (l >> 3);
  char* ksw = KsB + w * 1024;
  // V staging geometry: thread covers kv = t>>3 (+32), d0 = (t&7)*8.
  const int vkv = t >> 3, vd0 = (t & 7) * 8;
  unsigned short* Pw = Ps + w * 1152;
  const int sxor = cl & 7;
  for (int kvt = 0; kvt < 16; ++kvt) {
    const int kv0 = kvt * 64;
    __syncthreads();
    gload_lds16(Kg + (size_t)(kv0 + kr_l) * 64 + ku * 8, ksw);
    gload_lds16(Kg + (size_t)(kv0 + 32 + kr_l) * 64 + ku * 8, ksw + 4096);
    {
      const bf16x8 v0 = *(const bf16x8*)(Vg + (size_t)(kv0 + vkv) * 64 + vd0);
      const bf16x8 v1 = *(const bf16x8*)(Vg + (size_t)(kv0 + 32 + vkv) * 64 + vd0);
#pragma unroll
      for (int j = 0; j < 8; j++) {
        Vt[(vd0 + j) * 66 + vkv] = (unsigned short)v0[j];
        Vt[(vd0 + j) * 66 + 32 + vkv] = (unsigned short)v1[j];
      }
    }
    __syncthreads();
    f32x4 s[4] = {};
#pragma unroll
    for (int ch = 0; ch < 4; ch++) {
      const int rb = (16 * ch + cl) << 7;
      const bf16x8 bk0 = *(const bf16x8*)(KsB + rb + ((g ^ sxor) << 4));
      s[ch] = __builtin_amdgcn_mfma_f32_16x16x32_bf16(aq0, bk0, s[ch], 0, 0, 0);
      const bf16x8 bk1 = *(const bf16x8*)(KsB + rb + (((4 + g) ^ sxor) << 4));
      s[ch] = __builtin_amdgcn_mfma_f32_16x16x32_bf16(aq1, bk1, s[ch], 0, 0, 0);
    }
#pragma unroll
    for (int j = 0; j < 4; j++) {
      const float v0 = s[0][j] * 0.125f, v1 = s[1][j] * 0.125f;
      const float v2 = s[2][j] * 0.125f, v3 = s[3][j] * 0.125f;
      float pm = fmaxf(fmaxf(v0, v1), fmaxf(v2, v3));
#pragma unroll
      for (int off = 1; off < 16; off <<= 1) pm = fmaxf(pm, __shfl_xor(pm, off));
      const float nm = fmaxf(mrow[j], pm);
      const float al = __expf(mrow[j] - nm);
      const float p0 = __expf(v0 - nm), p1 = __expf(v1 - nm);
      const float p2 = __expf(v2 - nm), p3 = __expf(v3 - nm);
      float rs = (p0 + p1) + (p2 + p3);
#pragma unroll
      for (int off = 1; off < 16; off <<= 1) rs += __shfl_xor(rs, off);
      lrow[j] = lrow[j] * al + rs;
      mrow[j] = nm;
      o[0][j] *= al; o[1][j] *= al; o[2][j] *= al; o[3][j] *= al;
      const int pr = (g * 4 + j) * 72;
      Pw[pr + cl] = f2bu(p0);
      Pw[pr + 16 + cl] = f2bu(p1);
      Pw[pr + 32 + cl] = f2bu(p2);
      Pw[pr + 48 + cl] = f2bu(p3);
    }
    const bf16x8 pa0 = *(const bf16x8*)&Pw[cl * 72 + g * 8];
    const bf16x8 pa1 = *(const bf16x8*)&Pw[cl * 72 + 32 + g * 8];
#pragma unroll
    for (int dc = 0; dc < 4; dc++) {
      const int vr = (16 * dc + cl) * 66;
      const bf16x8 bv0 = *(const bf16x8*)&Vt[vr + g * 8];
      o[dc] = __builtin_amdgcn_mfma_f32_16x16x32_bf16(pa0, bv0, o[dc], 0, 0, 0);
      const bf16x8 bv1 = *(const bf16x8*)&Vt[vr + 32 + g * 8];
      o[dc] = __builtin_amdgcn_mfma_f32_16x16x32_bf16(pa1, bv1, o[dc], 0, 0, 0);
    }
  }
  const int b = bh >> 4, h = bh & 15;
#pragma unroll
  for (int j = 0; j < 4; j++) {
    const float inv = 1.f / lrow[j];
    const int q = q0 + w * 16 + g * 4 + j;
    const size_t base = ((size_t)(b * 1024 + q) * 16 + h) * 64;
    Ob[base + cl] = __float2bfloat16(o[0][j] * inv);
    Ob[base + 16 + cl] = __float2bfloat16(o[1][j] * inv);
    Ob[base + 32 + cl] = __float2bfloat16(o[2][j] * inv);
    Ob[base + 48 + cl] = __float2bfloat16(o[3][j] * inv);
  }
}

// ---------------- launch ----------------
extern "C" void kernel_launch(void* const* d_in, const int* in_sizes, int n_in,
                              void* d_out, int out_size, void* d_ws, size_t ws_size,
                              hipStream_t stream) {
  const float* x     = (const float*)d_in[0];
  const float* c     = (const float*)d_in[1];
  const float* n1w   = (const float*)d_in[2];
  const float* n2w   = (const float*)d_in[3];
  const float* qkvw  = (const float*)d_in[4];
  const float* projw = (const float*)d_in[5];
  const float* projb = (const float*)d_in[6];
  const float* qnw   = (const float*)d_in[7];
  const float* knw   = (const float*)d_in[8];
  const float* w1    = (const float*)d_in[9];
  const float* w2    = (const float*)d_in[10];
  const float* w3    = (const float*)d_in[11];
  const float* adaw  = (const float*)d_in[12];
  const float* adab  = (const float*)d_in[13];
  float* outp = (float*)d_out;
  char* ws = (char*)d_ws;
  if (ws_size < 93159424u) return;

  float* ropeC = (float*)(ws + 0);          // 131072
  float* ropeS = (float*)(ws + 131072);     // 131072
  float* mods  = (float*)(ws + 262144);     // 98304
  bf16* xmod   = (bf16*)(ws + 360448);      // 8388608
  bf16* qkvwt  = (bf16*)(ws + 8749056);     // 6291456  [3072][1024]
  bf16* projwt = (bf16*)(ws + 15040512);    // 2097152  [1024][1024]
  bf16* w1t    = (bf16*)(ws + 17137664);    // 5767168  [2816][1024] (rows>=2730 garbage, unused)
  bf16* w3t    = (bf16*)(ws + 22904832);    // 5767168
  bf16* w2t    = (bf16*)(ws + 28672000);    // 5767168  [1024][2816] (cols>=2730 zero)
  bf16* qkv    = (bf16*)(ws + 34439168);    // 25165824 [4096][3072]
  bf16* h1     = (bf16*)(ws + 34439168);    // reuse: [4096][2730]
  bf16* qb     = (bf16*)(ws + 59604992);    // 8388608 [64][1024][64]
  bf16* gbuf   = (bf16*)(ws + 59604992);    // reuse q/k/v: [4096][2816]
  bf16* kb     = (bf16*)(ws + 67993600);    // 8388608
  bf16* vb     = (bf16*)(ws + 76382208);    // 8388608
  bf16* ob     = (bf16*)(ws + 84770816);    // 8388608 [4096][1024] ([B][N][H][D])

  rope_tab<<<128, 256, 0, stream>>>(ropeC, ropeS);
  ada_mods<<<192, 256, 0, stream>>>(c, adaw, adab, mods);
  transpose_cast<<<dim3(96, 32), 256, 0, stream>>>(qkvw, 1024, 3072, qkvwt, 1024);
  transpose_cast<<<dim3(32, 32), 256, 0, stream>>>(projw, 1024, 1024, projwt, 1024);
  transpose_cast<<<dim3(86, 32), 256, 0, stream>>>(w1, 1024, 2730, w1t, 1024);
  transpose_cast<<<dim3(86, 32), 256, 0, stream>>>(w3, 1024, 2730, w3t, 1024);
  transpose_cast<<<dim3(32, 88), 256, 0, stream>>>(w2, 2730, 1024, w2t, 2816);

  // attention branch
  norm_mod<<<4096, 256, 0, stream>>>(x, n1w, mods, 0, 1024, xmod);
  gemm_bt<0><<<dim3(24, 32), 256, 0, stream>>>(xmod, 1024, qkvwt, 1024, 1024, 3072, 3072,
                                               qkv, nullptr, nullptr, nullptr, nullptr, nullptr, 0);
  qkv_post<<<16384, 256, 0, stream>>>(qkv, ropeC, ropeS, qnw, knw, qb, kb, vb);
  attn_fwd<<<dim3(16, 64), 256, 0, stream>>>(qb, kb, vb, ob);
  gemm_bt<1><<<dim3(8, 32), 256, 0, stream>>>(ob, 1024, projwt, 1024, 1024, 1024, 1024,
                                              nullptr, outp, x, mods + 2048, projb, nullptr, 0);

  // MLP branch
  norm_mod<<<4096, 256, 0, stream>>>(outp, n2w, mods, 3072, 4096, xmod);
  gemm_bt<0><<<dim3(22, 32), 256, 0, stream>>>(xmod, 1024, w1t, 1024, 1024, 2730, 2730,
                                               h1, nullptr, nullptr, nullptr, nullptr, nullptr, 0);
  gemm_bt<3><<<dim3(22, 32), 256, 0, stream>>>(xmod, 1024, w3t, 1024, 1024, 2730, 2816,
                                               gbuf, nullptr, nullptr, nullptr, nullptr, h1, 2730);
  gemm_bt<4><<<dim3(8, 32), 256, 0, stream>>>(gbuf, 2816, w2t, 2816, 2816, 1024, 1024,
                                              nullptr, outp, outp, mods + 5120, nullptr, nullptr, 0);
}